// Round 8
// baseline (195.417 us; speedup 1.0000x reference)
//
#include <hip/hip_runtime.h>
#include <math.h>

#define L_SEQ   16384
#define DMODEL  1024
#define NST     512             // complex states
#define CHUNK   128
#define NCHUNK  (L_SEQ / CHUNK) // 128
#define NT      16              // K-tiles per GEMM (1024 / 64)

typedef float  f32x4 __attribute__((ext_vector_type(4)));
typedef short  s16x8 __attribute__((ext_vector_type(8)));

__device__ __forceinline__ unsigned short f2bf(float f) {      // RNE
    union { float f; unsigned int u; } v; v.f = f;
    unsigned int r = v.u + 0x7fffu + ((v.u >> 16) & 1u);
    return (unsigned short)(r >> 16);
}
__device__ __forceinline__ unsigned short f2bf_fast(float f) { // round-half-up
    union { float f; unsigned int u; } v; v.f = f;
    return (unsigned short)((v.u + 0x8000u) >> 16);
}
__device__ __forceinline__ float bf2f(unsigned int h16) {
    union { unsigned int u; float f; } v; v.u = h16 << 16; return v.f;
}
__device__ __forceinline__ void mfma16(f32x4& d, s16x8 a, s16x8 b) {
    asm volatile("v_mfma_f32_16x16x32_bf16 %0, %1, %2, %0"
                 : "+v"(d) : "v"(a), "v"(b));
}
__device__ __forceinline__ uint4 pack8(float4 x, float4 y) {
    union { unsigned short u[8]; uint4 v; } t;
    t.u[0] = f2bf_fast(x.x); t.u[1] = f2bf_fast(x.y);
    t.u[2] = f2bf_fast(x.z); t.u[3] = f2bf_fast(x.w);
    t.u[4] = f2bf_fast(y.x); t.u[5] = f2bf_fast(y.y);
    t.u[6] = f2bf_fast(y.z); t.u[7] = f2bf_fast(y.w);
    return t.v;
}
// async global -> LDS, 16 bytes per lane (lane-linear LDS dest)
__device__ __forceinline__ void gload16(const unsigned short* g, unsigned short* l) {
    __builtin_amdgcn_global_load_lds(
        (const __attribute__((address_space(1))) unsigned int*)g,
        (__attribute__((address_space(3))) unsigned int*)l,
        16, 0, 0);
}
// raw barrier with compiler-level memory fence (no vmcnt/lgkm auto-drain)
__device__ __forceinline__ void bar() {
    asm volatile("" ::: "memory");
    __builtin_amdgcn_s_barrier();
    asm volatile("" ::: "memory");
}

// ---------------- setup: lambda, lambda^128, gamma ----------------
__global__ void setup_params(const float* __restrict__ nu_log,
                             const float* __restrict__ theta_log,
                             const float* __restrict__ gamma_log,
                             float* __restrict__ lam,    // [2][512]
                             float* __restrict__ lamT,   // lambda^128
                             float* __restrict__ gam) {
    int s = threadIdx.x;
    if (s >= NST) return;
    float mod = expf(-expf(nu_log[s]));
    float th  = expf(theta_log[s]);
    float ar = mod * cosf(th);
    float ai = mod * sinf(th);
    lam[s] = ar; lam[NST + s] = ai;
    gam[s] = expf(gamma_log[s]);
    float pr = 1.f, pi = 0.f;
    for (int i = 0; i < CHUNK; ++i) {
        float nr = pr * ar - pi * ai;
        float ni = pr * ai + pi * ar;
        pr = nr; pi = ni;
    }
    lamT[s] = pr; lamT[NST + s] = pi;
}

// W1 row 2s = Bre[s,:], row 2s+1 = Bim[s,:]  (no gamma; applied fp32 in scan)
__global__ void pack_w1(const float* __restrict__ Bre, const float* __restrict__ Bim,
                        unsigned short* __restrict__ W1) {
    int idx = blockIdx.x * 256 + threadIdx.x;
    int n = idx >> 10, k = idx & 1023;
    int s = n >> 1;
    float v = (n & 1) ? Bim[s * DMODEL + k] : Bre[s * DMODEL + k];
    W1[idx] = f2bf(v);
}
// W2[n][2s] = Cre[n][s], W2[n][2s+1] = -Cim[n][s]
__global__ void pack_w2(const float* __restrict__ Cre, const float* __restrict__ Cim,
                        unsigned short* __restrict__ W2) {
    int idx = blockIdx.x * 256 + threadIdx.x;
    int n = idx >> 10, k = idx & 1023;
    int s = k >> 1;
    float v = (k & 1) ? -Cim[n * NST + s] : Cre[n * NST + s];
    W2[idx] = f2bf(v);
}

// ---------------- X fp32 -> bf16 (8 elems/thread) ----------------
__global__ __launch_bounds__(256)
void conv_x(const float4* __restrict__ X, uint4* __restrict__ Xb) {
    int i = blockIdx.x * 256 + threadIdx.x;
    float4 a = X[2 * i], b = X[2 * i + 1];
    Xb[i] = pack8(a, b);
}

// ======== 256x256-tile, BK=64, 8-wave pipelined bf16 GEMM (counted vmcnt) ========
// LDS regions per buffer: [A_kx0, A_kx1, B_kx0, B_kx1], each [chunk4][row256][8elem]
// = 16 KB. Stage unit = one region (2 gload_lds). 1 unit staged per phase, stream
// runs 5 phases ahead; vmcnt(6) gate once per tile (never 0 until tile NT-2).
// Region last-read phases: A_kx0:ph0, B_kx0:ph1, A_kx1:ph2, B_kx1:ph3 -> re-stage
// for tile t+2 at the following phase is race-free with 2 buffers.

#define STAGE(BUF, OP, KX, T) do {                                              \
    const unsigned short* s_ = ((OP) ? Bsrc : Asrc) + (size_t)(T) * 64 + (KX) * 32; \
    gload16(s_,      &lds[BUF][(OP) * 2 + (KX)][tid * 8]);                      \
    gload16(s_ + 16, &lds[BUF][(OP) * 2 + (KX)][4096 + tid * 8]);               \
} while (0)

#define PH(BUF, Q, STG, GATE)                                                   \
  {                                                                             \
    if (((Q) & 1) == 0) {                                                       \
      _Pragma("unroll")                                                         \
      for (int m = 0; m < 8; ++m)                                               \
        af[m] = *(const s16x8*)&lds[BUF][(Q) >> 1]                              \
                 [g4 * 2048 + (wr * 128 + m * 16 + fr) * 8];                    \
    }                                                                           \
    s16x8 bfr[2];                                                               \
    _Pragma("unroll")                                                           \
    for (int j = 0; j < 2; ++j)                                                 \
      bfr[j] = *(const s16x8*)&lds[BUF][2 + ((Q) >> 1)]                         \
                [g4 * 2048 + (wc * 64 + ((Q) & 1) * 32 + j * 16 + fr) * 8];     \
    STG;                                                                        \
    bar();                                                                      \
    __builtin_amdgcn_s_setprio(1);                                              \
    _Pragma("unroll")                                                           \
    for (int m = 0; m < 8; ++m) {                                               \
      mfma16(acc[m][((Q) & 1) * 2 + 0], af[m], bfr[0]);                         \
      mfma16(acc[m][((Q) & 1) * 2 + 1], af[m], bfr[1]);                         \
    }                                                                           \
    __builtin_amdgcn_s_setprio(0);                                              \
    GATE;                                                                       \
    bar();                                                                      \
  }

template<int EPI>
__global__ __launch_bounds__(512)
void gemm_pipe(const unsigned short* __restrict__ A, const unsigned short* __restrict__ Bm,
               void* __restrict__ out, const float* __restrict__ Dv,
               const float* __restrict__ Xf) {
    __shared__ __align__(16) unsigned short lds[2][4][8192];   // 128 KiB

    const int tid  = threadIdx.x;
    const int lane = tid & 63;
    const int wave = tid >> 6;        // 0..7
    const int wr   = wave >> 2;       // 0..1  (M half)
    const int wc   = wave & 3;        // 0..3  (N quarter)
    const int fr   = lane & 15;
    const int g4   = lane >> 4;

    // XCD swizzle: 256 blocks, 32/XCD; bx inner => A-panel reuse within XCD
    const int lin   = blockIdx.x;
    const int n_new = (lin & 7) * 32 + (lin >> 3);
    const int bx = n_new & 3, by = n_new >> 2;
    const int m0 = by * 256, n0 = bx * 256;

    // per-lane global source: row = tid&255, k-chunk parity = tid>>8
    const unsigned short* Asrc = A  + (size_t)(m0 + (tid & 255)) * 1024 + (tid >> 8) * 8;
    const unsigned short* Bsrc = Bm + (size_t)(n0 + (tid & 255)) * 1024 + (tid >> 8) * 8;

    f32x4 acc[8][4] = {};
    s16x8 af[8];

    // prologue: FIFO = t0.{A0,B0,A1,B1}, t1.{A0,B0,A1}; retire t0 (8 loads)
    STAGE(0, 0, 0, 0); STAGE(0, 1, 0, 0); STAGE(0, 0, 1, 0); STAGE(0, 1, 1, 0);
    STAGE(1, 0, 0, 1); STAGE(1, 1, 0, 1); STAGE(1, 0, 1, 1);
    asm volatile("s_waitcnt vmcnt(6)" ::: "memory");
    bar();

    for (int t = 0; t < NT; ++t) {
        const int bb = t & 1;
        PH(bb, 0, { if (t + 1 < NT) STAGE(bb ^ 1, 1, 1, t + 1); }, {})
        PH(bb, 1, { if (t + 2 < NT) STAGE(bb, 0, 0, t + 2); }, {})
        PH(bb, 2, { if (t + 2 < NT) STAGE(bb, 1, 0, t + 2); }, {})
        PH(bb, 3, { if (t + 2 < NT) STAGE(bb, 0, 1, t + 2); },
           { if (t < NT - 2)       asm volatile("s_waitcnt vmcnt(6)" ::: "memory");
             else if (t == NT - 2) asm volatile("s_waitcnt vmcnt(0)" ::: "memory"); })
    }

    const int crow = (lane >> 4) * 4;   // C/D: col=lane&15, row=(lane>>4)*4+r
    const int ccol = lane & 15;
    #pragma unroll
    for (int mf = 0; mf < 8; ++mf) {
        #pragma unroll
        for (int j = 0; j < 4; ++j) {
            const int n  = n0 + wc * 64 + j * 16 + ccol;
            const int mb = m0 + wr * 128 + mf * 16 + crow;
            #pragma unroll
            for (int r = 0; r < 4; ++r) {
                const int m = mb + r;
                if (EPI) {
                    ((float*)out)[(size_t)m * 1024 + n] =
                        acc[mf][j][r] + Dv[n] * Xf[(size_t)m * 1024 + n];
                } else {
                    ((unsigned short*)out)[(size_t)m * 1024 + n] = f2bf(acc[mf][j][r]);
                }
            }
        }
    }
}

// ---------- scan pass 1: chunk ends only ----------
__global__ __launch_bounds__(128)
void scan_ends(const unsigned int* __restrict__ Bu, const float* __restrict__ lam,
               const float* __restrict__ gam, float* __restrict__ ends) {
    const int s = blockIdx.y * 128 + threadIdx.x;
    const int c = blockIdx.x;
    const float lr = lam[s], li = lam[NST + s], g = gam[s];
    float hr = 0.f, hi = 0.f;
    size_t base = (size_t)c * CHUNK * NST + s;
    #pragma unroll 4
    for (int t = 0; t < CHUNK; ++t) {
        unsigned int v = Bu[base + (size_t)t * NST];
        float br = g * bf2f(v & 0xffffu);
        float bi = g * bf2f(v >> 16);
        float nr = fmaf(lr, hr, fmaf(-li, hi, br));
        float ni = fmaf(lr, hi, fmaf( li, hr, bi));
        hr = nr; hi = ni;
    }
    ends[(size_t)(c * NST + s) * 2]     = hr;
    ends[(size_t)(c * NST + s) * 2 + 1] = hi;
}

// ---------- carry scan across chunks ----------
__global__ __launch_bounds__(NST)
void scan_carry(const float* __restrict__ ends, const float* __restrict__ lamT,
                float* __restrict__ car) {
    const int s = threadIdx.x;
    const float ar = lamT[s], ai = lamT[NST + s];
    float cr = 0.f, ci = 0.f;
    for (int c = 0; c < NCHUNK; ++c) {
        car[(size_t)(c * NST + s) * 2]     = cr;
        car[(size_t)(c * NST + s) * 2 + 1] = ci;
        float er = ends[(size_t)(c * NST + s) * 2];
        float ei = ends[(size_t)(c * NST + s) * 2 + 1];
        float nr = fmaf(ar, cr, fmaf(-ai, ci, er));
        float ni = fmaf(ar, ci, fmaf( ai, cr, ei));
        cr = nr; ci = ni;
    }
}

// ---------- scan pass 2: full scan from carry, write H bf16 (to Xb region) ----
__global__ __launch_bounds__(128)
void scan_h(const unsigned int* __restrict__ Bu, unsigned int* __restrict__ H,
            const float* __restrict__ lam, const float* __restrict__ gam,
            const float* __restrict__ car) {
    const int s = blockIdx.y * 128 + threadIdx.x;
    const int c = blockIdx.x;
    const float lr = lam[s], li = lam[NST + s], g = gam[s];
    float hr = car[(size_t)(c * NST + s) * 2];
    float hi = car[(size_t)(c * NST + s) * 2 + 1];
    size_t base = (size_t)c * CHUNK * NST + s;
    #pragma unroll 4
    for (int t = 0; t < CHUNK; ++t) {
        unsigned int v = Bu[base + (size_t)t * NST];
        float br = g * bf2f(v & 0xffffu);
        float bi = g * bf2f(v >> 16);
        float nr = fmaf(lr, hr, fmaf(-li, hi, br));
        float ni = fmaf(lr, hi, fmaf( li, hr, bi));
        hr = nr; hi = ni;
        H[base + (size_t)t * NST] =
            (unsigned int)f2bf(hr) | ((unsigned int)f2bf(hi) << 16);
    }
}

extern "C" void kernel_launch(void* const* d_in, const int* in_sizes, int n_in,
                              void* d_out, int out_size, void* d_ws, size_t ws_size,
                              hipStream_t stream) {
    const float* X         = (const float*)d_in[0];
    const float* nu_log    = (const float*)d_in[1];
    const float* theta_log = (const float*)d_in[2];
    const float* gamma_log = (const float*)d_in[3];
    const float* Bre       = (const float*)d_in[4];
    const float* Bim       = (const float*)d_in[5];
    const float* Cre       = (const float*)d_in[6];
    const float* Cim       = (const float*)d_in[7];
    const float* Dv        = (const float*)d_in[8];
    float* Y = (float*)d_out;

    // ws (~37 MB): Xb (later reused as H), W1, W2, small tables.
    // Bu (bf16 pairs, 32 MB) lives in d_out's first 32 MB; dead before gemm2 writes Y.
    char* ws = (char*)d_ws;
    size_t off = 0;
    unsigned short* Xb  = (unsigned short*)(ws + off); off += (size_t)L_SEQ * DMODEL * 2;  // 32MB
    unsigned short* H   = Xb;   // reuse: Xb dead after gemm1
    unsigned short* W1  = (unsigned short*)(ws + off); off += (size_t)DMODEL * DMODEL * 2; // 2MB
    unsigned short* W2  = (unsigned short*)(ws + off); off += (size_t)DMODEL * DMODEL * 2; // 2MB
    float* lam  = (float*)(ws + off); off += 1024 * 4;
    float* lamT = (float*)(ws + off); off += 1024 * 4;
    float* gam  = (float*)(ws + off); off += 512 * 4;
    float* ends = (float*)(ws + off); off += (size_t)NCHUNK * NST * 2 * 4;  // 512KB
    float* car  = (float*)(ws + off); off += (size_t)NCHUNK * NST * 2 * 4;  // 512KB
    unsigned short* Bu = (unsigned short*)d_out;

    setup_params<<<1, NST, 0, stream>>>(nu_log, theta_log, gamma_log, lam, lamT, gam);
    pack_w1<<<(DMODEL * DMODEL) / 256, 256, 0, stream>>>(Bre, Bim, W1);
    pack_w2<<<(DMODEL * DMODEL) / 256, 256, 0, stream>>>(Cre, Cim, W2);
    conv_x<<<(L_SEQ * DMODEL / 8) / 256, 256, 0, stream>>>((const float4*)X, (uint4*)Xb);

    gemm_pipe<0><<<256, 512, 0, stream>>>(Xb, W1, Bu, nullptr, nullptr);

    dim3 gs(NCHUNK, 4);   // 128 chunks x 4 state-groups of 128
    scan_ends<<<gs, 128, 0, stream>>>((const unsigned int*)Bu, lam, gam, ends);
    scan_carry<<<1, NST, 0, stream>>>(ends, lamT, car);
    scan_h<<<gs, 128, 0, stream>>>((const unsigned int*)Bu, (unsigned int*)H, lam, gam, car);

    gemm_pipe<1><<<256, 512, 0, stream>>>(H, W2, Y, Dv, X);
}